// Round 5
// baseline (62.760 us; speedup 1.0000x reference)
//
#include <hip/hip_runtime.h>
#include <hip/hip_bf16.h>

using bf16x8 = __bf16 __attribute__((ext_vector_type(8)));
using f32x4  = float __attribute__((ext_vector_type(4)));

constexpr int HWT   = 784;
constexpr int CIN   = 64;
constexpr int DOUT  = 128;
constexpr int BATCH = 512;
constexpr int NROWS = BATCH * HWT;               // 401408
constexpr int ROWS_PER_BLOCK = 128;
constexpr int NBLOCKS = NROWS / ROWS_PER_BLOCK;  // 3136

// out[n, d] = sum_c x[partner(n), c] * W[d, c]; partner = XOR within batch pair.
// attn output (appended) = all ones (size-1 softmax).
// R3 structure (58.9us): LDS-transposed epilogue, row-contiguous dwordx4 stores.
// R4: nontemporal stores (write-once stream) + nontemporal x loads (read-once,
// bijective partner map) to keep L2/L3 clean; W stays cached (reused 3136x).
__global__ __launch_bounds__(256)
void qkv_xor_gemm(const float* __restrict__ x,
                  const float* __restrict__ W,
                  float* __restrict__ out)
{
  __shared__ union LdsU {
    __bf16 w[DOUT][72];     // 18432 B  (W staging, phase 1)
    float  tr[4][16][68];   // 17408 B  (per-wave transpose, phase 2)
  } lds;

  const int tid  = threadIdx.x;
  const int lane = tid & 63;
  const int wave = tid >> 6;
  const int nidx = lane & 15;          // fragment non-K index
  const int krow = (lane >> 4) * 8;    // K base per lane group
  const int grp  = lane >> 4;          // lane group 0..3

  // ---- phase 1: stage W (fp32 [128][64]) -> bf16 LDS (cached loads: W is hot)
  {
    const f32x4* W4 = reinterpret_cast<const f32x4*>(W);
    for (int i = tid; i < DOUT * CIN / 4; i += 256) {
      f32x4 wv = W4[i];
      int d = i >> 4;
      int c = (i & 15) * 4;
      lds.w[d][c + 0] = (__bf16)wv[0];
      lds.w[d][c + 1] = (__bf16)wv[1];
      lds.w[d][c + 2] = (__bf16)wv[2];
      lds.w[d][c + 3] = (__bf16)wv[3];
    }
  }
  __syncthreads();

  // ---- W fragments (B operand): lane holds W[dt*16 + nidx][kt*32 + krow + j]
  bf16x8 bfrag[8][2];
#pragma unroll
  for (int dt = 0; dt < 8; ++dt) {
#pragma unroll
    for (int kt = 0; kt < 2; ++kt) {
      bfrag[dt][kt] =
          *reinterpret_cast<const bf16x8*>(&lds.w[dt * 16 + nidx][kt * 32 + krow]);
    }
  }
  __syncthreads();   // all waves done reading W; buffer now reusable as tr

#pragma unroll
  for (int rt = 0; rt < 2; ++rt) {
    const int rbase = blockIdx.x * ROWS_PER_BLOCK + rt * 64 + wave * 16;

    // A fragment: row = rbase + nidx (XOR-partner source), k = krow..krow+7
    const int r   = rbase + nidx;
    const int b   = r / HWT;
    const int t   = r - b * HWT;
    const int src = (b ^ 1) * HWT + t;
    const float* xp = x + (size_t)src * CIN + krow;
    f32x4 x0 = __builtin_nontemporal_load(reinterpret_cast<const f32x4*>(xp));
    f32x4 x1 = __builtin_nontemporal_load(reinterpret_cast<const f32x4*>(xp + 4));
    f32x4 x2 = __builtin_nontemporal_load(reinterpret_cast<const f32x4*>(xp + 32));
    f32x4 x3 = __builtin_nontemporal_load(reinterpret_cast<const f32x4*>(xp + 36));

    bf16x8 a0, a1;
#pragma unroll
    for (int i = 0; i < 4; ++i) {
      a0[i]     = (__bf16)x0[i];
      a0[i + 4] = (__bf16)x1[i];
      a1[i]     = (__bf16)x2[i];
      a1[i + 4] = (__bf16)x3[i];
    }

    f32x4 acc[8];
#pragma unroll
    for (int dt = 0; dt < 8; ++dt) acc[dt] = (f32x4){0.f, 0.f, 0.f, 0.f};
#pragma unroll
    for (int dt = 0; dt < 8; ++dt) {
      acc[dt] = __builtin_amdgcn_mfma_f32_16x16x32_bf16(a0, bfrag[dt][0], acc[dt], 0, 0, 0);
      acc[dt] = __builtin_amdgcn_mfma_f32_16x16x32_bf16(a1, bfrag[dt][1], acc[dt], 0, 0, 0);
    }

    // ---- epilogue: per-wave LDS transpose, 2 column-halves of 64
    // acc layout (m89): local row = grp*4 + i, local col = dt*16 + nidx
#pragma unroll
    for (int p = 0; p < 2; ++p) {
#pragma unroll
      for (int d4 = 0; d4 < 4; ++d4) {
#pragma unroll
        for (int i = 0; i < 4; ++i) {
          lds.tr[wave][grp * 4 + i][d4 * 16 + nidx] = acc[p * 4 + d4][i];
        }
      }
      // read back row-contiguous: r = 4q + grp, c = (lane&15)*4 .. +3
#pragma unroll
      for (int q = 0; q < 4; ++q) {
        f32x4 v = *reinterpret_cast<const f32x4*>(&lds.tr[wave][4 * q + grp][nidx * 4]);
        __builtin_nontemporal_store(
            v, reinterpret_cast<f32x4*>(
                   out + (size_t)(rbase + 4 * q + grp) * DOUT + p * 64 + nidx * 4));
      }
    }
  }

  // attn output: ones [NROWS] appended after cross_x
  if (tid < ROWS_PER_BLOCK) {
    __builtin_nontemporal_store(
        1.0f, out + (size_t)NROWS * DOUT + (size_t)blockIdx.x * ROWS_PER_BLOCK + tid);
  }
}

extern "C" void kernel_launch(void* const* d_in, const int* in_sizes, int n_in,
                              void* d_out, int out_size, void* d_ws, size_t ws_size,
                              hipStream_t stream)
{
  const float* x = (const float*)d_in[0];
  const float* W = (const float*)d_in[1];
  float* out = (float*)d_out;
  qkv_xor_gemm<<<NBLOCKS, 256, 0, stream>>>(x, W, out);
}

// Round 6
// 58.585 us; speedup vs baseline: 1.0713x; 1.0713x over previous
//
#include <hip/hip_runtime.h>
#include <hip/hip_bf16.h>

using bf16x8 = __bf16 __attribute__((ext_vector_type(8)));
using f32x4  = float __attribute__((ext_vector_type(4)));

constexpr int HWT   = 784;
constexpr int CIN   = 64;
constexpr int DOUT  = 128;
constexpr int BATCH = 512;
constexpr int NROWS = BATCH * HWT;               // 401408
constexpr int ROWS_PER_BLOCK = 128;
constexpr int NBLOCKS = NROWS / ROWS_PER_BLOCK;  // 3136

// out[n, d] = sum_c x[partner(n), c] * W[d, c]; partner = XOR within batch pair.
// attn output (appended) = all ones (size-1 softmax).
//
// R5: MFMA operand order A=W, B=x (layout verified PASS in R1):
//   lane (g=lane>>4, n=lane&15) holds, per acc[dt], cols dt*16+4g..+3 of
//   row rbase+n  -> f32x4 per lane -> epilogue LDS writes are ds_write_b128
//   (8 per rt vs 32 b32 in R3). tr stride 66 floats -> <=2-way banks both
//   sides. Global stores identical to R3 (row-contiguous dwordx4, full lines).
// No nontemporal anything (R4 regressed: x loads need half-line L1 reuse).
__global__ __launch_bounds__(256)
void qkv_xor_gemm(const float* __restrict__ x,
                  const float* __restrict__ W,
                  float* __restrict__ out)
{
  __shared__ union LdsU {
    __bf16 w[DOUT][72];     // 18432 B  (W staging, phase 1)
    float  tr[4][16][66];   // 16896 B  (per-wave transpose, phase 2)
  } lds;

  const int tid  = threadIdx.x;
  const int lane = tid & 63;
  const int wave = tid >> 6;
  const int nidx = lane & 15;          // fragment non-K index
  const int grp  = lane >> 4;          // lane group 0..3
  const int krow = grp * 8;            // K base per lane group

  // ---- phase 1: stage W (fp32 [128][64]) -> bf16 LDS
  {
    const f32x4* W4 = reinterpret_cast<const f32x4*>(W);
    for (int i = tid; i < DOUT * CIN / 4; i += 256) {
      f32x4 wv = W4[i];
      int d = i >> 4;
      int c = (i & 15) * 4;
      lds.w[d][c + 0] = (__bf16)wv[0];
      lds.w[d][c + 1] = (__bf16)wv[1];
      lds.w[d][c + 2] = (__bf16)wv[2];
      lds.w[d][c + 3] = (__bf16)wv[3];
    }
  }
  __syncthreads();

  // ---- W fragments (A operand): lane holds W[dt*16 + nidx][kt*32 + krow + j]
  bf16x8 wfrag[8][2];
#pragma unroll
  for (int dt = 0; dt < 8; ++dt) {
#pragma unroll
    for (int kt = 0; kt < 2; ++kt) {
      wfrag[dt][kt] =
          *reinterpret_cast<const bf16x8*>(&lds.w[dt * 16 + nidx][kt * 32 + krow]);
    }
  }
  __syncthreads();   // all waves done reading W; buffer now reusable as tr

#pragma unroll
  for (int rt = 0; rt < 2; ++rt) {
    const int rbase = blockIdx.x * ROWS_PER_BLOCK + rt * 64 + wave * 16;

    // x fragment (B operand): lane holds x[partner(rbase + nidx)][kt*32 + krow + j]
    const int r   = rbase + nidx;
    const int b   = r / HWT;
    const int t   = r - b * HWT;
    const int src = (b ^ 1) * HWT + t;
    const float* xp = x + (size_t)src * CIN + krow;
    f32x4 x0 = *reinterpret_cast<const f32x4*>(xp);
    f32x4 x1 = *reinterpret_cast<const f32x4*>(xp + 4);
    f32x4 x2 = *reinterpret_cast<const f32x4*>(xp + 32);
    f32x4 x3 = *reinterpret_cast<const f32x4*>(xp + 36);

    bf16x8 bx0, bx1;
#pragma unroll
    for (int i = 0; i < 4; ++i) {
      bx0[i]     = (__bf16)x0[i];
      bx0[i + 4] = (__bf16)x1[i];
      bx1[i]     = (__bf16)x2[i];
      bx1[i + 4] = (__bf16)x3[i];
    }

    f32x4 acc[8];
#pragma unroll
    for (int dt = 0; dt < 8; ++dt) acc[dt] = (f32x4){0.f, 0.f, 0.f, 0.f};
#pragma unroll
    for (int dt = 0; dt < 8; ++dt) {
      acc[dt] = __builtin_amdgcn_mfma_f32_16x16x32_bf16(wfrag[dt][0], bx0, acc[dt], 0, 0, 0);
      acc[dt] = __builtin_amdgcn_mfma_f32_16x16x32_bf16(wfrag[dt][1], bx1, acc[dt], 0, 0, 0);
    }

    // ---- epilogue: per-wave LDS transpose in two 64-col halves.
    // acc[dt] = cols dt*16 + 4*grp .. +3 of row (rbase + nidx)   [R1-verified]
#pragma unroll
    for (int p = 0; p < 2; ++p) {
#pragma unroll
      for (int d4 = 0; d4 < 4; ++d4) {
        *reinterpret_cast<f32x4*>(&lds.tr[wave][nidx][d4 * 16 + 4 * grp]) =
            acc[p * 4 + d4];
      }
      // read row-contiguous: local row = 4q + grp, cols 4*nidx .. +3
#pragma unroll
      for (int q = 0; q < 4; ++q) {
        f32x4 v = *reinterpret_cast<const f32x4*>(&lds.tr[wave][4 * q + grp][4 * nidx]);
        *reinterpret_cast<f32x4*>(
            out + (size_t)(rbase + 4 * q + grp) * DOUT + p * 64 + 4 * nidx) = v;
      }
    }
  }

  // attn output: ones [NROWS] appended after cross_x
  if (tid < ROWS_PER_BLOCK) {
    out[(size_t)NROWS * DOUT + (size_t)blockIdx.x * ROWS_PER_BLOCK + tid] = 1.0f;
  }
}

extern "C" void kernel_launch(void* const* d_in, const int* in_sizes, int n_in,
                              void* d_out, int out_size, void* d_ws, size_t ws_size,
                              hipStream_t stream)
{
  const float* x = (const float*)d_in[0];
  const float* W = (const float*)d_in[1];
  float* out = (float*)d_out;
  qkv_xor_gemm<<<NBLOCKS, 256, 0, stream>>>(x, W, out);
}